// Round 7
// baseline (736.007 us; speedup 1.0000x reference)
//
#include <hip/hip_runtime.h>

#define S    8192
#define Dm   4096
#define E    64
#define CAP  128
#define CCH  8           // split-K chunks
#define KC   (Dm/CCH)    // 512 k per chunk
#define KSUB 16          // k sub-tile staged in LDS
#define TB   128         // tokens per K1 block
#define XSTR 132         // xs row stride: 2-way store conflicts only (free)
#define WSTR 68          // ws row stride: 2-way store conflicts only (free)

#define CW_OFF 1
#define DM_OFF (1 + (size_t)S*E*CAP)
#define EC_OFF (1 + 2*(size_t)S*E*CAP)

// ---------------- K1: register-tiled partial GEMM ---------------------------
// block: 128 tokens x 64 experts x 512 k. thread: 4 tokens x 8 experts (acc[32]).
// Register-prefetch pipeline: global loads for su+1 issued before compute(su).
__global__ __launch_bounds__(256, 4)
void k1_partial(const float* __restrict__ x, const float* __restrict__ wg,
                float* __restrict__ part) {
    __shared__ float xs[KSUB][XSTR];   // [k][token]
    __shared__ float wsh[KSUB][WSTR];  // [k][e]
    const int tb  = blockIdx.x >> 3;   // 0..63 token block
    const int c   = blockIdx.x & 7;    // 0..7 k chunk
    const int tid = threadIdx.x;
    const int tg  = tid & 31;          // token group (4 tokens)
    const int ee  = tid >> 5;          // expert group (8 experts)
    const int k0  = c * KC;

    float acc[32];
    #pragma unroll
    for (int i = 0; i < 32; i++) acc[i] = 0.f;

    const int xrow = tid >> 2;         // 0..63
    const int xcol = tid & 3;          // float4 col within 16 k
    const int we   = tid >> 2;         // expert for W staging
    const int wk   = (tid & 3) * 4;    // k quad for W staging

    const float* xp0 = x  + (size_t)(tb*TB + xrow)      * Dm + k0 + xcol*4;
    const float* xp1 = x  + (size_t)(tb*TB + xrow + 64) * Dm + k0 + xcol*4;
    const float* wp  = wg + (size_t)we * Dm + k0 + wk;

    float4 va0 = *(const float4*)xp0;
    float4 va1 = *(const float4*)xp1;
    float4 vw  = *(const float4*)wp;

    for (int su = 0; su < KC / KSUB; su++) {
        xs[xcol*4+0][xrow]    = va0.x; xs[xcol*4+1][xrow]    = va0.y;
        xs[xcol*4+2][xrow]    = va0.z; xs[xcol*4+3][xrow]    = va0.w;
        xs[xcol*4+0][xrow+64] = va1.x; xs[xcol*4+1][xrow+64] = va1.y;
        xs[xcol*4+2][xrow+64] = va1.z; xs[xcol*4+3][xrow+64] = va1.w;
        wsh[wk+0][we] = vw.x; wsh[wk+1][we] = vw.y;
        wsh[wk+2][we] = vw.z; wsh[wk+3][we] = vw.w;
        __syncthreads();
        if (su < KC/KSUB - 1) {            // prefetch next sub-tile
            va0 = *(const float4*)(xp0 + (su+1)*KSUB);
            va1 = *(const float4*)(xp1 + (su+1)*KSUB);
            vw  = *(const float4*)(wp  + (su+1)*KSUB);
        }
        #pragma unroll
        for (int kk = 0; kk < KSUB; kk++) {
            const float4 a  = *(const float4*)&xs[kk][tg*4];
            const float4 w0 = *(const float4*)&wsh[kk][ee*8];
            const float4 w1 = *(const float4*)&wsh[kk][ee*8+4];
            const float av[4] = {a.x, a.y, a.z, a.w};
            const float wv[8] = {w0.x,w0.y,w0.z,w0.w,w1.x,w1.y,w1.z,w1.w};
            #pragma unroll
            for (int t = 0; t < 4; t++)
                #pragma unroll
                for (int e = 0; e < 8; e++)
                    acc[t*8+e] = fmaf(av[t], wv[e], acc[t*8+e]);
        }
        __syncthreads();
    }
    // part[c][token][e]
    #pragma unroll
    for (int t = 0; t < 4; t++) {
        float* dst = part + ((size_t)c * S + tb*TB + tg*4 + t) * E + ee*8;
        *(float4*)(dst)     = make_float4(acc[t*8+0], acc[t*8+1], acc[t*8+2], acc[t*8+3]);
        *(float4*)(dst + 4) = make_float4(acc[t*8+4], acc[t*8+5], acc[t*8+6], acc[t*8+7]);
    }
}

// ---------------- K1b: reduce partials, softmax, argmax, me atomics ----------
__global__ __launch_bounds__(256, 1)
void k1b_softmax(const float* __restrict__ part, float* __restrict__ gate_val,
                 int* __restrict__ idx1, int* __restrict__ counts,
                 float* __restrict__ me_sum) {
    const int tid = threadIdx.x, wv = tid >> 6, ln = tid & 63;
    const int token = blockIdx.x * 4 + wv;
    float p = 0.f;
    #pragma unroll
    for (int c = 0; c < CCH; c++) p += part[((size_t)c * S + token) * E + ln];
    // argmax (max value, lowest index on ties) — matches jnp.argmax
    float v = p; int i = ln;
    #pragma unroll
    for (int off = 1; off < 64; off <<= 1) {
        float ov = __shfl_xor(v, off, 64);
        int   oi = __shfl_xor(i, off, 64);
        if (ov > v || (ov == v && oi < i)) { v = ov; i = oi; }
    }
    float g = __expf(p - v);
    float ssum = g;
    #pragma unroll
    for (int off = 1; off < 64; off <<= 1) ssum += __shfl_xor(ssum, off, 64);
    const float gate = g / ssum;
    __shared__ float gs[4][64];
    gs[wv][ln] = gate;
    __syncthreads();
    if (tid < 64)
        atomicAdd(&me_sum[tid], gs[0][tid] + gs[1][tid] + gs[2][tid] + gs[3][tid]);
    if (ln == 0) {
        gate_val[token] = 1.0f / ssum;
        idx1[token] = i;
        atomicAdd(&counts[i], 1);
    }
}

// ---------------- K2: per-expert capacity selection -> sel_pos ---------------
__device__ __forceinline__ int block_reduce_sum(int v, int* tmp4, int tid) {
    #pragma unroll
    for (int off = 1; off < 64; off <<= 1) v += __shfl_xor(v, off, 64);
    __syncthreads();
    if ((tid & 63) == 0) tmp4[tid >> 6] = v;
    __syncthreads();
    return tmp4[0] + tmp4[1] + tmp4[2] + tmp4[3];
}

__device__ __forceinline__ int block_scan_incl(int val, int* a, int* b, int tid, int* total) {
    __syncthreads();
    a[tid] = val;
    __syncthreads();
    int* src = a; int* dst = b;
    #pragma unroll
    for (int off = 1; off < 256; off <<= 1) {
        int v = src[tid];
        if (tid >= off) v += src[tid - off];
        dst[tid] = v;
        __syncthreads();
        int* t = src; src = dst; dst = t;
    }
    *total = src[255];
    return src[tid];
}

__global__ __launch_bounds__(256, 1)
void k2_select(const int* __restrict__ idx1, const float* __restrict__ noise,
               const int* __restrict__ counts, const float* __restrict__ me_sum,
               int* __restrict__ sel_pos, float* __restrict__ out) {
    const int e = blockIdx.x;
    const int tid = threadIdx.x;
    __shared__ int idx_s[S];
    __shared__ unsigned short l_tok[S];
    __shared__ float l_ns[S];
    __shared__ int sa[256], sb[256];
    __shared__ int tmp4[4];

    for (int i = tid; i < S; i += 256) idx_s[i] = idx1[i];
    __syncthreads();

    int cnt = 0;
    #pragma unroll
    for (int j4 = 0; j4 < 8; j4++) {
        const int4 q = *(const int4*)&idx_s[tid * 32 + j4 * 4];
        cnt += (q.x == e) + (q.y == e) + (q.z == e) + (q.w == e);
    }
    int total_n;
    int incl = block_scan_incl(cnt, sa, sb, tid, &total_n);
    int pos = incl - cnt;
    const int n = total_n;
    #pragma unroll
    for (int j4 = 0; j4 < 8; j4++) {
        const int4 q = *(const int4*)&idx_s[tid * 32 + j4 * 4];
        const int qv[4] = {q.x, q.y, q.z, q.w};
        #pragma unroll
        for (int u = 0; u < 4; u++) {
            const int s = tid * 32 + j4 * 4 + u;
            if (qv[u] == e) {
                l_tok[pos] = (unsigned short)s;
                l_ns[pos]  = noise[(size_t)s * E + e];
                pos++;
            }
        }
    }
    __syncthreads();

    if (tid == 0) out[EC_OFF + e] = (float)n;   // exp_counts (pre-capacity)

    // 128th-largest noise via binary search on positive-float bit patterns
    unsigned int V = 0u;
    if (n > CAP) {
        unsigned int lo = 0u, hi = 0x3F800000u;
        while (hi - lo > 1u) {
            const unsigned int mid = (lo + hi) >> 1;
            int c = 0;
            for (int i2 = tid; i2 < n; i2 += 256)
                c += (__float_as_uint(l_ns[i2]) >= mid);
            const int cge = block_reduce_sum(c, tmp4, tid);
            if (cge >= CAP) lo = mid; else hi = mid;
        }
        V = lo;
    }

    const int m = (n + 255) >> 8;
    const int i_begin = min(n, tid * m);
    const int i_end   = min(n, i_begin + m);
    int gt_l = 0, eq_l = 0;
    for (int i2 = i_begin; i2 < i_end; i2++) {
        const unsigned int b = __float_as_uint(l_ns[i2]);
        gt_l += (b > V); eq_l += (b == V);
    }
    int tot_gt, tot_eq;
    const int incl_gt = block_scan_incl(gt_l, sa, sb, tid, &tot_gt);
    (void)incl_gt;
    const int incl_eq = block_scan_incl(eq_l, sa, sb, tid, &tot_eq);
    const int eq_excl = incl_eq - eq_l;
    const int take_eq = CAP - tot_gt;   // ties -> lowest token index (jax top_k stable)
    const int sel_l = gt_l + max(0, min(eq_l, take_eq - eq_excl));
    int tot_sel;
    const int incl_sel = block_scan_incl(sel_l, sa, sb, tid, &tot_sel);
    int slot = incl_sel - sel_l;
    int eq_seen = eq_excl;
    for (int i2 = i_begin; i2 < i_end; i2++) {
        const unsigned int b = __float_as_uint(l_ns[i2]);
        bool sel;
        if (b > V) sel = true;
        else if (b == V) { sel = (eq_seen < take_eq); eq_seen++; }
        else sel = false;
        const int tok = l_tok[i2];
        if (sel) { sel_pos[tok] = e * CAP + slot; slot++; }
        else     { sel_pos[tok] = -1; }
    }

    if (e == 0 && tid < 64) {
        float la = (me_sum[tid] / (float)S) * ((float)counts[tid] / (float)S);
        #pragma unroll
        for (int off = 1; off < 64; off <<= 1) la += __shfl_xor(la, off, 64);
        if (tid == 0) out[0] = la * (float)E;
    }
}

// ---------------- K3: fused zero-fill + scatter over combine/dispatch --------
// 4 tokens per block; unit-stride dword streams (CW_OFF=1 breaks 16B align).
__global__ __launch_bounds__(256)
void k3_fill(const int* __restrict__ sel_pos, const float* __restrict__ gate_val,
             float* __restrict__ out) {
    const int tid  = threadIdx.x;
    const int tok0 = blockIdx.x * 4;
    #pragma unroll
    for (int t = 0; t < 4; t++) {
        const int tok = tok0 + t;
        const int pos = sel_pos[tok];
        const float g = gate_val[tok];
        float* cw = out + CW_OFF + (size_t)tok * (E * CAP);
        float* dm = cw + (size_t)S * (E * CAP);
        #pragma unroll
        for (int j = 0; j < 8; j++) {
            const int b = j * 1024 + tid;
            #pragma unroll
            for (int q = 0; q < 4; q++) {
                const int idx = b + q * 256;
                cw[idx] = (idx == pos) ? g   : 0.f;
                dm[idx] = (idx == pos) ? 1.f : 0.f;
            }
        }
    }
}

extern "C" void kernel_launch(void* const* d_in, const int* in_sizes, int n_in,
                              void* d_out, int out_size, void* d_ws, size_t ws_size,
                              hipStream_t stream) {
    const float* x     = (const float*)d_in[0];
    const float* wg    = (const float*)d_in[1];
    const float* noise = (const float*)d_in[2];
    float* out = (float*)d_out;
    float* ws  = (float*)d_ws;

    float* gate_val = ws;                   // 8192 f32
    int*   idx1     = (int*)(ws + 8192);    // 8192 i32
    int*   counts   = (int*)(ws + 16384);   // 64 i32
    float* me_sum   = ws + 16448;           // 64 f32
    int*   sel_pos  = (int*)(ws + 16512);   // 8192 i32
    float* part     = ws + 24704;           // 8*8192*64 f32 = 16.8 MB

    hipMemsetAsync(counts, 0, 128 * sizeof(int), stream);      // counts + me_sum
    k1_partial  <<<dim3(512),  dim3(256), 0, stream>>>(x, wg, part);
    k1b_softmax <<<dim3(S/4),  dim3(256), 0, stream>>>(part, gate_val, idx1, counts, me_sum);
    k2_select   <<<dim3(E),    dim3(256), 0, stream>>>(idx1, noise, counts, me_sum, sel_pos, out);
    k3_fill     <<<dim3(S/4),  dim3(256), 0, stream>>>(sel_pos, gate_val, out);
}